// Round 11
// baseline (835.480 us; speedup 1.0000x reference)
//
#include <hip/hip_runtime.h>
#include <cmath>

#define T_TOK 8192
#define HDIM 1024
#define IDIM 4096
#define NEXP 8

#define OFF_LOSS  8388608
#define OFF_USAGE 8388609
#define OFF_TOPE  8388617

typedef __attribute__((ext_vector_type(8))) short bf16x8;
typedef __attribute__((ext_vector_type(4))) float f32x4;
typedef unsigned short u16;
typedef unsigned int u32;

__device__ inline u16 f2bf(float f) {
  u32 u = __float_as_uint(f);
  u32 r = (u + 0x7FFFu + ((u >> 16) & 1u)) >> 16;
  return (u16)r;
}

// tanh-form gelu via fast exp; max |err| vs exact-erf gelu ~3e-3 (budget 0.14).
__device__ inline float gelu_fast(float v) {
  float u = v + 0.044715f * v * v * v;
  return v / (1.0f + __expf(-1.5957691216f * u));
}

__device__ inline void glds16(const void* g, void* l) {
  __builtin_amdgcn_global_load_lds(
      (const __attribute__((address_space(1))) u32*)g,
      (__attribute__((address_space(3))) u32*)l, 16, 0, 0);
}

// ------- transpose+convert: src [E][R][C] f32 -> dst [E][C][R] bf16, 64x64 tile ------
__global__ __launch_bounds__(256)
void transpose_cvt64(const float* __restrict__ src, u16* __restrict__ dst, int R, int C) {
  __shared__ float tile[64][65];
  size_t eoff = (size_t)blockIdx.z * R * C;
  int r0 = blockIdx.y * 64, c0 = blockIdx.x * 64;
  const float* s = src + eoff;
  u16* d = dst + eoff;
  int tr = threadIdx.x >> 4;
  int tc = (threadIdx.x & 15) * 4;
#pragma unroll
  for (int it = 0; it < 4; it++) {
    int row = tr + it * 16;
    float4 v = *(const float4*)(s + (size_t)(r0 + row) * C + c0 + tc);
    tile[row][tc] = v.x; tile[row][tc + 1] = v.y;
    tile[row][tc + 2] = v.z; tile[row][tc + 3] = v.w;
  }
  __syncthreads();
  int wc = threadIdx.x >> 3;
  int wr = (threadIdx.x & 7) * 8;
#pragma unroll
  for (int it = 0; it < 2; it++) {
    int c = wc + it * 32;
    union { u16 s[8]; uint4 v; } u;
#pragma unroll
    for (int j = 0; j < 8; j++) u.s[j] = f2bf(tile[wr + j][c]);
    *(uint4*)(d + (size_t)(c0 + c) * R + r0 + wr) = u.v;
  }
}

// ---- router: f64 logits/softmax/top2, 4 tokens/block; also emits xb (bf16 x) ----
__global__ __launch_bounds__(256)
void router_kernel(const float* __restrict__ x, const float* __restrict__ gw,
                   u16* __restrict__ xb,
                   float* __restrict__ probs, int* __restrict__ counts,
                   int* __restrict__ tlist, float* __restrict__ wlist,
                   float* __restrict__ out) {
  int wid = threadIdx.x >> 6, lane = threadIdx.x & 63;
  int tok = blockIdx.x * 4 + wid;
  double acc[NEXP];
#pragma unroll
  for (int e = 0; e < NEXP; e++) acc[e] = 0.0;
  const float* xr = x + (size_t)tok * HDIM;
  u16* xbr = xb + (size_t)tok * HDIM;
#pragma unroll
  for (int i = 0; i < 4; i++) {
    int h0 = (lane + i * 64) * 4;
    float4 v = *(const float4*)(xr + h0);
    union { u16 s[4]; uint2 u; } cv;
    cv.s[0] = f2bf(v.x); cv.s[1] = f2bf(v.y);
    cv.s[2] = f2bf(v.z); cv.s[3] = f2bf(v.w);
    *(uint2*)(xbr + h0) = cv.u;
    const float* g0 = gw + (size_t)h0 * NEXP;
#pragma unroll
    for (int e = 0; e < NEXP; e++)
      acc[e] += (double)v.x * (double)g0[e] +
                (double)v.y * (double)g0[NEXP + e] +
                (double)v.z * (double)g0[2 * NEXP + e] +
                (double)v.w * (double)g0[3 * NEXP + e];
  }
#pragma unroll
  for (int off = 32; off > 0; off >>= 1) {
#pragma unroll
    for (int e = 0; e < NEXP; e++) acc[e] += __shfl_xor(acc[e], off);
  }
  if (lane == 0) {
    double m = acc[0];
#pragma unroll
    for (int e = 1; e < NEXP; e++) if (acc[e] > m) m = acc[e];
    double p[NEXP], ssum = 0.0;
#pragma unroll
    for (int e = 0; e < NEXP; e++) { p[e] = exp(acc[e] - m); ssum += p[e]; }
#pragma unroll
    for (int e = 0; e < NEXP; e++) p[e] /= ssum;
    int i1 = 0;
#pragma unroll
    for (int e = 1; e < NEXP; e++) if (p[e] > p[i1]) i1 = e;
    int i2 = (i1 == 0) ? 1 : 0;
#pragma unroll
    for (int e = 0; e < NEXP; e++) if (e != i1 && p[e] > p[i2]) i2 = e;
    double ps = p[i1] + p[i2];
#pragma unroll
    for (int e = 0; e < NEXP; e++) probs[(size_t)tok * NEXP + e] = (float)p[e];
    out[OFF_TOPE + tok] = (float)i1;
    int pos1 = atomicAdd(&counts[i1], 1);
    tlist[i1 * T_TOK + pos1] = tok;
    wlist[i1 * T_TOK + pos1] = (float)(p[i1] / ps);
    int pos2 = atomicAdd(&counts[i2], 1);
    tlist[i2 * T_TOK + pos2] = tok;
    wlist[i2 * T_TOK + pos2] = (float)(p[i2] / ps);
  }
}

__global__ void hbase_kernel(const int* __restrict__ counts, int* __restrict__ hbase) {
  if (threadIdx.x == 0 && blockIdx.x == 0) {
    int s = 0;
    for (int e = 0; e < NEXP; e++) { hbase[e] = s; s += counts[e]; }
    hbase[NEXP] = s;
  }
}

__global__ __launch_bounds__(256)
void usage_kernel(const float* __restrict__ probs, float* __restrict__ out) {
  int e = blockIdx.x;
  float s = 0.f;
  for (int t = threadIdx.x; t < T_TOK; t += 256) s += probs[(size_t)t * NEXP + e];
#pragma unroll
  for (int off = 32; off > 0; off >>= 1) s += __shfl_xor(s, off);
  __shared__ float red[4];
  int lane = threadIdx.x & 63, wid = threadIdx.x >> 6;
  if (lane == 0) red[wid] = s;
  __syncthreads();
  if (threadIdx.x == 0)
    out[OFF_USAGE + e] = (red[0] + red[1] + red[2] + red[3]) / (float)T_TOK;
}

__global__ void loss_kernel(float* __restrict__ out) {
  if (threadIdx.x == 0 && blockIdx.x == 0) {
    float s = 0.f;
    for (int e = 0; e < NEXP; e++) { float u = out[OFF_USAGE + e]; s += u * u; }
    out[OFF_LOSS] = (float)NEXP * s;
  }
}

// ======== 128x128 BK=32 GEMMs, 256 thr (4 waves 2x2), dbuf 32KB, counted vmcnt ====
// R5/R10 schedule frozen. New: __launch_bounds__(256,4) to force <=128 regs
// (acc 64 AGPR + ~64 VGPR) -> 4 waves/SIMD occupancy tier; L2-aware tile orders.

// ---------------- up GEMM: h = gelu(x[tok] @ up_w[e] + up_b[e]) ----------------
// Tile order: e / tn / tm (tm inner): 64 consecutive blocks share a 256KB B-tile;
// per-expert gathered A ~4MB ~ L2.
__global__ __launch_bounds__(256, 4)
void up_gemm(const u16* __restrict__ xb, const u16* __restrict__ wbt,
             const float* __restrict__ bias, const int* __restrict__ counts,
             const int* __restrict__ hbase, const int* __restrict__ tlist,
             u16* __restrict__ hout, int e_fixed) {
  const int NT = IDIM / 128;   // 32
  const int MT = T_TOK / 128;  // 64
  int q = gridDim.x >> 3;
  int orig = blockIdx.x;
  int wg = (orig & 7) * q + (orig >> 3);   // XCD-chunked, bijective (nwg%8==0)
  int e, r;
  if (e_fixed >= 0) { e = e_fixed; r = wg; }
  else { e = wg / (MT * NT); r = wg % (MT * NT); }
  int tn = r / MT;
  int tm = r % MT;
  int cnt = counts[e];
  int m0 = tm * 128;
  if (m0 >= cnt) return;
  int hb = (e_fixed >= 0) ? 0 : hbase[e];
  int n0 = tn * 128;

  __shared__ u16 As[2 * 4096];
  __shared__ u16 Bs[2 * 4096];

  int t = threadIdx.x;
  int ra = t >> 2;
  int sw = (t & 3) ^ ((ra >> 1) & 3);

  const int* tl = tlist + e * T_TOK;
  int g0 = m0 + ra;      if (g0 > cnt - 1) g0 = cnt - 1;
  int g1 = m0 + ra + 64; if (g1 > cnt - 1) g1 = cnt - 1;
  const u16* pa0 = xb + (size_t)tl[g0] * HDIM + sw * 8;
  const u16* pa1 = xb + (size_t)tl[g1] * HDIM + sw * 8;
  const u16* wb = wbt + (size_t)e * IDIM * HDIM;
  const u16* pb0 = wb + (size_t)(n0 + ra) * HDIM + sw * 8;
  const u16* pb1 = wb + (size_t)(n0 + ra + 64) * HDIM + sw * 8;

  f32x4 acc[4][4];
#pragma unroll
  for (int i = 0; i < 4; i++)
#pragma unroll
    for (int j = 0; j < 4; j++) acc[i][j] = (f32x4){0.f, 0.f, 0.f, 0.f};

  int lane = t & 63, wid = t >> 6;
  int wr = (wid >> 1) * 64, wc = (wid & 1) * 64;
  int lrow = lane & 15, lslot = lane >> 4;

  auto stage = [&](int b, int k0) {
    u16* a = &As[b * 4096];
    u16* bb = &Bs[b * 4096];
    glds16(pa0 + k0, a + t * 8);
    glds16(pa1 + k0, a + 2048 + t * 8);
    glds16(pb0 + k0, bb + t * 8);
    glds16(pb1 + k0, bb + 2048 + t * 8);
  };
  auto compute = [&](int b) {
    const u16* A = &As[b * 4096];
    const u16* Bb = &Bs[b * 4096];
    bf16x8 af[4], bfv[4];
#pragma unroll
    for (int mi = 0; mi < 4; mi++) {
      int row = wr + mi * 16 + lrow;
      af[mi] = *(const bf16x8*)&A[row * 32 + ((lslot ^ ((row >> 1) & 3)) * 8)];
    }
#pragma unroll
    for (int ni = 0; ni < 4; ni++) {
      int row = wc + ni * 16 + lrow;
      bfv[ni] = *(const bf16x8*)&Bb[row * 32 + ((lslot ^ ((row >> 1) & 3)) * 8)];
    }
#pragma unroll
    for (int mi = 0; mi < 4; mi++)
#pragma unroll
      for (int ni = 0; ni < 4; ni++)
        acc[mi][ni] = __builtin_amdgcn_mfma_f32_16x16x32_bf16(af[mi], bfv[ni], acc[mi][ni], 0, 0, 0);
  };

  const int nk = HDIM / 32;  // 32
  stage(0, 0);
  for (int kt = 0; kt < nk; ++kt) {
    int b = kt & 1;
    __builtin_amdgcn_s_barrier();
    if (kt + 1 < nk) {
      stage(b ^ 1, (kt + 1) * 32);
      asm volatile("s_waitcnt vmcnt(4)" ::: "memory");
    } else {
      asm volatile("s_waitcnt vmcnt(0)" ::: "memory");
    }
    compute(b);
  }

  float bv[4];
#pragma unroll
  for (int ni = 0; ni < 4; ni++)
    bv[ni] = bias[(size_t)e * IDIM + n0 + wc + ni * 16 + lrow];
  int r4 = lslot * 4;
#pragma unroll
  for (int mi = 0; mi < 4; mi++) {
    int rb = m0 + wr + mi * 16 + r4;
#pragma unroll
    for (int j = 0; j < 4; j++) {
      int row = rb + j;
      if (row < cnt) {
        u16* hp = hout + (size_t)(hb + row) * IDIM + n0 + wc + lrow;
#pragma unroll
        for (int ni = 0; ni < 4; ni++) {
          float v = acc[mi][ni][j] + bv[ni];
          hp[ni * 16] = f2bf(gelu_fast(v));
        }
      }
    }
  }
}

// ------- down GEMM, SPLIT-K=4: out[tok] += w * (h @ down_w[e] + down_b[e]) -------
// Tile order: e / ks / tm / tn (tn inner): one XCD streams one 2MB B-quarter per
// ks-pass through L2; 8 tn-blocks share each 256KB A-tile.
__global__ __launch_bounds__(256, 4)
void down_gemm(const u16* __restrict__ h, const u16* __restrict__ wbt,
               const float* __restrict__ bias, const int* __restrict__ counts,
               const int* __restrict__ hbase, const int* __restrict__ tlist,
               const float* __restrict__ wlist, float* __restrict__ out, int e_fixed) {
  const int NT = HDIM / 128;   // 8
  const int MT = T_TOK / 128;  // 64
  const int KS = 4;
  int q = gridDim.x >> 3;
  int orig = blockIdx.x;
  int wg = (orig & 7) * q + (orig >> 3);
  int e, r;
  if (e_fixed >= 0) { e = e_fixed; r = wg; }
  else { e = wg / (KS * MT * NT); r = wg % (KS * MT * NT); }
  int ks = r / (MT * NT);
  int r2 = r % (MT * NT);
  int tm = r2 / NT;
  int tn = r2 % NT;
  int cnt = counts[e];
  int m0 = tm * 128;
  if (m0 >= cnt) return;
  int hb = (e_fixed >= 0) ? 0 : hbase[e];
  int n0 = tn * 128;
  int kbase = ks * (IDIM / KS);   // 0,1024,2048,3072

  __shared__ u16 As[2 * 4096];
  __shared__ u16 Bs[2 * 4096];

  int t = threadIdx.x;
  int ra = t >> 2;
  int sw = (t & 3) ^ ((ra >> 1) & 3);

  int g0 = m0 + ra;      if (g0 > cnt - 1) g0 = cnt - 1;
  int g1 = m0 + ra + 64; if (g1 > cnt - 1) g1 = cnt - 1;
  const u16* pa0 = h + (size_t)(hb + g0) * IDIM + kbase + sw * 8;
  const u16* pa1 = h + (size_t)(hb + g1) * IDIM + kbase + sw * 8;
  const u16* wb = wbt + (size_t)e * HDIM * IDIM;
  const u16* pb0 = wb + (size_t)(n0 + ra) * IDIM + kbase + sw * 8;
  const u16* pb1 = wb + (size_t)(n0 + ra + 64) * IDIM + kbase + sw * 8;

  f32x4 acc[4][4];
#pragma unroll
  for (int i = 0; i < 4; i++)
#pragma unroll
    for (int j = 0; j < 4; j++) acc[i][j] = (f32x4){0.f, 0.f, 0.f, 0.f};

  int lane = t & 63, wid = t >> 6;
  int wr = (wid >> 1) * 64, wc = (wid & 1) * 64;
  int lrow = lane & 15, lslot = lane >> 4;

  auto stage = [&](int b, int k0) {
    u16* a = &As[b * 4096];
    u16* bb = &Bs[b * 4096];
    glds16(pa0 + k0, a + t * 8);
    glds16(pa1 + k0, a + 2048 + t * 8);
    glds16(pb0 + k0, bb + t * 8);
    glds16(pb1 + k0, bb + 2048 + t * 8);
  };
  auto compute = [&](int b) {
    const u16* A = &As[b * 4096];
    const u16* Bb = &Bs[b * 4096];
    bf16x8 af[4], bfv[4];
#pragma unroll
    for (int mi = 0; mi < 4; mi++) {
      int row = wr + mi * 16 + lrow;
      af[mi] = *(const bf16x8*)&A[row * 32 + ((lslot ^ ((row >> 1) & 3)) * 8)];
    }
#pragma unroll
    for (int ni = 0; ni < 4; ni++) {
      int row = wc + ni * 16 + lrow;
      bfv[ni] = *(const bf16x8*)&Bb[row * 32 + ((lslot ^ ((row >> 1) & 3)) * 8)];
    }
#pragma unroll
    for (int mi = 0; mi < 4; mi++)
#pragma unroll
      for (int ni = 0; ni < 4; ni++)
        acc[mi][ni] = __builtin_amdgcn_mfma_f32_16x16x32_bf16(af[mi], bfv[ni], acc[mi][ni], 0, 0, 0);
  };

  const int nk = (IDIM / KS) / 32;  // 32
  stage(0, 0);
  for (int kt = 0; kt < nk; ++kt) {
    int b = kt & 1;
    __builtin_amdgcn_s_barrier();
    if (kt + 1 < nk) {
      stage(b ^ 1, (kt + 1) * 32);
      asm volatile("s_waitcnt vmcnt(4)" ::: "memory");
    } else {
      asm volatile("s_waitcnt vmcnt(0)" ::: "memory");
    }
    compute(b);
  }

  float bv[4];
#pragma unroll
  for (int ni = 0; ni < 4; ni++)
    bv[ni] = (ks == 0) ? bias[(size_t)e * HDIM + n0 + wc + ni * 16 + lrow] : 0.0f;
  int r4 = lslot * 4;
#pragma unroll
  for (int mi = 0; mi < 4; mi++) {
    int rb = m0 + wr + mi * 16 + r4;
#pragma unroll
    for (int j = 0; j < 4; j++) {
      int row = rb + j;
      if (row < cnt) {
        int tok = tlist[e * T_TOK + row];
        float w = wlist[e * T_TOK + row];
        float* op = out + (size_t)tok * HDIM + n0 + wc + lrow;
#pragma unroll
        for (int ni = 0; ni < 4; ni++)
          atomicAdd(&op[ni * 16], w * (acc[mi][ni][j] + bv[ni]));
      }
    }
  }
}

extern "C" void kernel_launch(void* const* d_in, const int* in_sizes, int n_in,
                              void* d_out, int out_size, void* d_ws, size_t ws_size,
                              hipStream_t stream) {
  const float* x   = (const float*)d_in[0];
  const float* gw  = (const float*)d_in[1];
  const float* upw = (const float*)d_in[2];
  const float* upb = (const float*)d_in[3];
  const float* dnw = (const float*)d_in[4];
  const float* dnb = (const float*)d_in[5];
  float* out = (float*)d_out;
  char* ws = (char*)d_ws;

  int*   counts = (int*)(ws + 0);
  int*   hbase  = (int*)(ws + 64);
  int*   tlist  = (int*)(ws + 256);
  float* wlist  = (float*)(ws + 256 + 262144);
  float* probs  = (float*)(ws + 256 + 2 * 262144);
  u16*   xb     = (u16*)(ws + 1048576);
  u16*   upbt   = (u16*)(ws + 1048576 + 16777216);
  u16*   dnbt   = (u16*)(ws + 1048576 + 16777216 + 67108864ull);
  u16*   hbuf   = (u16*)(ws + 1048576 + 16777216 + 2ull * 67108864ull);

  bool grouped = ws_size >= 286261248ull;

  hipMemsetAsync(counts, 0, 32, stream);
  hipMemsetAsync(d_out, 0, (size_t)out_size * 4, stream);

  transpose_cvt64<<<dim3(IDIM / 64, HDIM / 64, NEXP), 256, 0, stream>>>(upw, upbt, HDIM, IDIM);
  transpose_cvt64<<<dim3(HDIM / 64, IDIM / 64, NEXP), 256, 0, stream>>>(dnw, dnbt, IDIM, HDIM);
  router_kernel<<<T_TOK / 4, 256, 0, stream>>>(x, gw, xb, probs, counts, tlist, wlist, out);
  hbase_kernel<<<1, 64, 0, stream>>>(counts, hbase);
  usage_kernel<<<NEXP, 256, 0, stream>>>(probs, out);
  loss_kernel<<<1, 64, 0, stream>>>(out);

  if (grouped) {
    up_gemm<<<NEXP * 64 * 32, 256, 0, stream>>>(xb, upbt, upb, counts, hbase, tlist, hbuf, -1);
    down_gemm<<<NEXP * 64 * 8 * 4, 256, 0, stream>>>(hbuf, dnbt, dnb, counts, hbase, tlist, wlist, out, -1);
  } else {
    for (int e = 0; e < NEXP; e++) {
      up_gemm<<<64 * 32, 256, 0, stream>>>(xb, upbt, upb, counts, hbase, tlist, hbuf, e);
      down_gemm<<<64 * 8 * 4, 256, 0, stream>>>(hbuf, dnbt, dnb, counts, hbase, tlist, wlist, out, e);
    }
  }
}

// Round 12
// 767.452 us; speedup vs baseline: 1.0886x; 1.0886x over previous
//
#include <hip/hip_runtime.h>
#include <cmath>

#define T_TOK 8192
#define HDIM 1024
#define IDIM 4096
#define NEXP 8

#define OFF_LOSS  8388608
#define OFF_USAGE 8388609
#define OFF_TOPE  8388617

typedef __attribute__((ext_vector_type(8))) short bf16x8;
typedef __attribute__((ext_vector_type(4))) float f32x4;
typedef unsigned short u16;
typedef unsigned int u32;

__device__ inline u16 f2bf(float f) {
  u32 u = __float_as_uint(f);
  u32 r = (u + 0x7FFFu + ((u >> 16) & 1u)) >> 16;
  return (u16)r;
}

// tanh-form gelu via fast exp; max |err| vs exact-erf gelu ~3e-3 (budget 0.14).
__device__ inline float gelu_fast(float v) {
  float u = v + 0.044715f * v * v * v;
  return v / (1.0f + __expf(-1.5957691216f * u));
}

__device__ inline void glds16(const void* g, void* l) {
  __builtin_amdgcn_global_load_lds(
      (const __attribute__((address_space(1))) u32*)g,
      (__attribute__((address_space(3))) u32*)l, 16, 0, 0);
}

// ------- transpose+convert: src [E][R][C] f32 -> dst [E][C][R] bf16, 64x64 tile ------
__global__ __launch_bounds__(256)
void transpose_cvt64(const float* __restrict__ src, u16* __restrict__ dst, int R, int C) {
  __shared__ float tile[64][65];
  size_t eoff = (size_t)blockIdx.z * R * C;
  int r0 = blockIdx.y * 64, c0 = blockIdx.x * 64;
  const float* s = src + eoff;
  u16* d = dst + eoff;
  int tr = threadIdx.x >> 4;
  int tc = (threadIdx.x & 15) * 4;
#pragma unroll
  for (int it = 0; it < 4; it++) {
    int row = tr + it * 16;
    float4 v = *(const float4*)(s + (size_t)(r0 + row) * C + c0 + tc);
    tile[row][tc] = v.x; tile[row][tc + 1] = v.y;
    tile[row][tc + 2] = v.z; tile[row][tc + 3] = v.w;
  }
  __syncthreads();
  int wc = threadIdx.x >> 3;
  int wr = (threadIdx.x & 7) * 8;
#pragma unroll
  for (int it = 0; it < 2; it++) {
    int c = wc + it * 32;
    union { u16 s[8]; uint4 v; } u;
#pragma unroll
    for (int j = 0; j < 8; j++) u.s[j] = f2bf(tile[wr + j][c]);
    *(uint4*)(d + (size_t)(c0 + c) * R + r0 + wr) = u.v;
  }
}

// ---- router: f64 logits/softmax/top2, 4 tokens/block; also emits xb (bf16 x) ----
__global__ __launch_bounds__(256)
void router_kernel(const float* __restrict__ x, const float* __restrict__ gw,
                   u16* __restrict__ xb,
                   float* __restrict__ probs, int* __restrict__ counts,
                   int* __restrict__ tlist, float* __restrict__ wlist,
                   float* __restrict__ out) {
  int wid = threadIdx.x >> 6, lane = threadIdx.x & 63;
  int tok = blockIdx.x * 4 + wid;
  double acc[NEXP];
#pragma unroll
  for (int e = 0; e < NEXP; e++) acc[e] = 0.0;
  const float* xr = x + (size_t)tok * HDIM;
  u16* xbr = xb + (size_t)tok * HDIM;
#pragma unroll
  for (int i = 0; i < 4; i++) {
    int h0 = (lane + i * 64) * 4;
    float4 v = *(const float4*)(xr + h0);
    union { u16 s[4]; uint2 u; } cv;
    cv.s[0] = f2bf(v.x); cv.s[1] = f2bf(v.y);
    cv.s[2] = f2bf(v.z); cv.s[3] = f2bf(v.w);
    *(uint2*)(xbr + h0) = cv.u;
    const float* g0 = gw + (size_t)h0 * NEXP;
#pragma unroll
    for (int e = 0; e < NEXP; e++)
      acc[e] += (double)v.x * (double)g0[e] +
                (double)v.y * (double)g0[NEXP + e] +
                (double)v.z * (double)g0[2 * NEXP + e] +
                (double)v.w * (double)g0[3 * NEXP + e];
  }
#pragma unroll
  for (int off = 32; off > 0; off >>= 1) {
#pragma unroll
    for (int e = 0; e < NEXP; e++) acc[e] += __shfl_xor(acc[e], off);
  }
  if (lane == 0) {
    double m = acc[0];
#pragma unroll
    for (int e = 1; e < NEXP; e++) if (acc[e] > m) m = acc[e];
    double p[NEXP], ssum = 0.0;
#pragma unroll
    for (int e = 0; e < NEXP; e++) { p[e] = exp(acc[e] - m); ssum += p[e]; }
#pragma unroll
    for (int e = 0; e < NEXP; e++) p[e] /= ssum;
    int i1 = 0;
#pragma unroll
    for (int e = 1; e < NEXP; e++) if (p[e] > p[i1]) i1 = e;
    int i2 = (i1 == 0) ? 1 : 0;
#pragma unroll
    for (int e = 0; e < NEXP; e++) if (e != i1 && p[e] > p[i2]) i2 = e;
    double ps = p[i1] + p[i2];
#pragma unroll
    for (int e = 0; e < NEXP; e++) probs[(size_t)tok * NEXP + e] = (float)p[e];
    out[OFF_TOPE + tok] = (float)i1;
    int pos1 = atomicAdd(&counts[i1], 1);
    tlist[i1 * T_TOK + pos1] = tok;
    wlist[i1 * T_TOK + pos1] = (float)(p[i1] / ps);
    int pos2 = atomicAdd(&counts[i2], 1);
    tlist[i2 * T_TOK + pos2] = tok;
    wlist[i2 * T_TOK + pos2] = (float)(p[i2] / ps);
  }
}

__global__ void hbase_kernel(const int* __restrict__ counts, int* __restrict__ hbase) {
  if (threadIdx.x == 0 && blockIdx.x == 0) {
    int s = 0;
    for (int e = 0; e < NEXP; e++) { hbase[e] = s; s += counts[e]; }
    hbase[NEXP] = s;
  }
}

__global__ __launch_bounds__(256)
void usage_kernel(const float* __restrict__ probs, float* __restrict__ out) {
  int e = blockIdx.x;
  float s = 0.f;
  for (int t = threadIdx.x; t < T_TOK; t += 256) s += probs[(size_t)t * NEXP + e];
#pragma unroll
  for (int off = 32; off > 0; off >>= 1) s += __shfl_xor(s, off);
  __shared__ float red[4];
  int lane = threadIdx.x & 63, wid = threadIdx.x >> 6;
  if (lane == 0) red[wid] = s;
  __syncthreads();
  if (threadIdx.x == 0)
    out[OFF_USAGE + e] = (red[0] + red[1] + red[2] + red[3]) / (float)T_TOK;
}

__global__ void loss_kernel(float* __restrict__ out) {
  if (threadIdx.x == 0 && blockIdx.x == 0) {
    float s = 0.f;
    for (int e = 0; e < NEXP; e++) { float u = out[OFF_USAGE + e]; s += u * u; }
    out[OFF_LOSS] = (float)NEXP * s;
  }
}

// ======== 128x128 BK=32 GEMMs, 256 thr (4 waves 2x2), dbuf 32KB, counted vmcnt ====
// R10 schedule + __launch_bounds__(256,4) (proven: VGPR 72->56, occ 32->41%).
// Down reverted to SPLIT-K=2 (R11's KS=4 doubled atomic WRITE to 256MB: net loss).

// ---------------- up GEMM: h = gelu(x[tok] @ up_w[e] + up_b[e]) ----------------
// Tile order: e / tn / tm (tm inner): 64 consecutive blocks share a 256KB B-tile.
__global__ __launch_bounds__(256, 4)
void up_gemm(const u16* __restrict__ xb, const u16* __restrict__ wbt,
             const float* __restrict__ bias, const int* __restrict__ counts,
             const int* __restrict__ hbase, const int* __restrict__ tlist,
             u16* __restrict__ hout, int e_fixed) {
  const int NT = IDIM / 128;   // 32
  const int MT = T_TOK / 128;  // 64
  int q = gridDim.x >> 3;
  int orig = blockIdx.x;
  int wg = (orig & 7) * q + (orig >> 3);   // XCD-chunked, bijective (nwg%8==0)
  int e, r;
  if (e_fixed >= 0) { e = e_fixed; r = wg; }
  else { e = wg / (MT * NT); r = wg % (MT * NT); }
  int tn = r / MT;
  int tm = r % MT;
  int cnt = counts[e];
  int m0 = tm * 128;
  if (m0 >= cnt) return;
  int hb = (e_fixed >= 0) ? 0 : hbase[e];
  int n0 = tn * 128;

  __shared__ u16 As[2 * 4096];
  __shared__ u16 Bs[2 * 4096];

  int t = threadIdx.x;
  int ra = t >> 2;
  int sw = (t & 3) ^ ((ra >> 1) & 3);

  const int* tl = tlist + e * T_TOK;
  int g0 = m0 + ra;      if (g0 > cnt - 1) g0 = cnt - 1;
  int g1 = m0 + ra + 64; if (g1 > cnt - 1) g1 = cnt - 1;
  const u16* pa0 = xb + (size_t)tl[g0] * HDIM + sw * 8;
  const u16* pa1 = xb + (size_t)tl[g1] * HDIM + sw * 8;
  const u16* wb = wbt + (size_t)e * IDIM * HDIM;
  const u16* pb0 = wb + (size_t)(n0 + ra) * HDIM + sw * 8;
  const u16* pb1 = wb + (size_t)(n0 + ra + 64) * HDIM + sw * 8;

  f32x4 acc[4][4];
#pragma unroll
  for (int i = 0; i < 4; i++)
#pragma unroll
    for (int j = 0; j < 4; j++) acc[i][j] = (f32x4){0.f, 0.f, 0.f, 0.f};

  int lane = t & 63, wid = t >> 6;
  int wr = (wid >> 1) * 64, wc = (wid & 1) * 64;
  int lrow = lane & 15, lslot = lane >> 4;

  auto stage = [&](int b, int k0) {
    u16* a = &As[b * 4096];
    u16* bb = &Bs[b * 4096];
    glds16(pa0 + k0, a + t * 8);
    glds16(pa1 + k0, a + 2048 + t * 8);
    glds16(pb0 + k0, bb + t * 8);
    glds16(pb1 + k0, bb + 2048 + t * 8);
  };
  auto compute = [&](int b) {
    const u16* A = &As[b * 4096];
    const u16* Bb = &Bs[b * 4096];
    bf16x8 af[4], bfv[4];
#pragma unroll
    for (int mi = 0; mi < 4; mi++) {
      int row = wr + mi * 16 + lrow;
      af[mi] = *(const bf16x8*)&A[row * 32 + ((lslot ^ ((row >> 1) & 3)) * 8)];
    }
#pragma unroll
    for (int ni = 0; ni < 4; ni++) {
      int row = wc + ni * 16 + lrow;
      bfv[ni] = *(const bf16x8*)&Bb[row * 32 + ((lslot ^ ((row >> 1) & 3)) * 8)];
    }
#pragma unroll
    for (int mi = 0; mi < 4; mi++)
#pragma unroll
      for (int ni = 0; ni < 4; ni++)
        acc[mi][ni] = __builtin_amdgcn_mfma_f32_16x16x32_bf16(af[mi], bfv[ni], acc[mi][ni], 0, 0, 0);
  };

  const int nk = HDIM / 32;  // 32
  stage(0, 0);
  for (int kt = 0; kt < nk; ++kt) {
    int b = kt & 1;
    __builtin_amdgcn_s_barrier();
    if (kt + 1 < nk) {
      stage(b ^ 1, (kt + 1) * 32);
      asm volatile("s_waitcnt vmcnt(4)" ::: "memory");
    } else {
      asm volatile("s_waitcnt vmcnt(0)" ::: "memory");
    }
    compute(b);
  }

  float bv[4];
#pragma unroll
  for (int ni = 0; ni < 4; ni++)
    bv[ni] = bias[(size_t)e * IDIM + n0 + wc + ni * 16 + lrow];
  int r4 = lslot * 4;
#pragma unroll
  for (int mi = 0; mi < 4; mi++) {
    int rb = m0 + wr + mi * 16 + r4;
#pragma unroll
    for (int j = 0; j < 4; j++) {
      int row = rb + j;
      if (row < cnt) {
        u16* hp = hout + (size_t)(hb + row) * IDIM + n0 + wc + lrow;
#pragma unroll
        for (int ni = 0; ni < 4; ni++) {
          float v = acc[mi][ni][j] + bv[ni];
          hp[ni * 16] = f2bf(gelu_fast(v));
        }
      }
    }
  }
}

// ------- down GEMM, SPLIT-K=2: out[tok] += w * (h @ down_w[e] + down_b[e]) -------
// Tile order: e / ks / tm / tn (tn inner): one XCD streams one 4MB B-half per
// ks-pass through L2; 8 tn-blocks share each 256KB A-tile.
__global__ __launch_bounds__(256, 4)
void down_gemm(const u16* __restrict__ h, const u16* __restrict__ wbt,
               const float* __restrict__ bias, const int* __restrict__ counts,
               const int* __restrict__ hbase, const int* __restrict__ tlist,
               const float* __restrict__ wlist, float* __restrict__ out, int e_fixed) {
  const int NT = HDIM / 128;   // 8
  const int MT = T_TOK / 128;  // 64
  const int KS = 2;
  int q = gridDim.x >> 3;
  int orig = blockIdx.x;
  int wg = (orig & 7) * q + (orig >> 3);
  int e, r;
  if (e_fixed >= 0) { e = e_fixed; r = wg; }
  else { e = wg / (KS * MT * NT); r = wg % (KS * MT * NT); }
  int ks = r / (MT * NT);
  int r2 = r % (MT * NT);
  int tm = r2 / NT;
  int tn = r2 % NT;
  int cnt = counts[e];
  int m0 = tm * 128;
  if (m0 >= cnt) return;
  int hb = (e_fixed >= 0) ? 0 : hbase[e];
  int n0 = tn * 128;
  int kbase = ks * (IDIM / KS);   // 0 or 2048

  __shared__ u16 As[2 * 4096];
  __shared__ u16 Bs[2 * 4096];

  int t = threadIdx.x;
  int ra = t >> 2;
  int sw = (t & 3) ^ ((ra >> 1) & 3);

  int g0 = m0 + ra;      if (g0 > cnt - 1) g0 = cnt - 1;
  int g1 = m0 + ra + 64; if (g1 > cnt - 1) g1 = cnt - 1;
  const u16* pa0 = h + (size_t)(hb + g0) * IDIM + kbase + sw * 8;
  const u16* pa1 = h + (size_t)(hb + g1) * IDIM + kbase + sw * 8;
  const u16* wb = wbt + (size_t)e * HDIM * IDIM;
  const u16* pb0 = wb + (size_t)(n0 + ra) * IDIM + kbase + sw * 8;
  const u16* pb1 = wb + (size_t)(n0 + ra + 64) * IDIM + kbase + sw * 8;

  f32x4 acc[4][4];
#pragma unroll
  for (int i = 0; i < 4; i++)
#pragma unroll
    for (int j = 0; j < 4; j++) acc[i][j] = (f32x4){0.f, 0.f, 0.f, 0.f};

  int lane = t & 63, wid = t >> 6;
  int wr = (wid >> 1) * 64, wc = (wid & 1) * 64;
  int lrow = lane & 15, lslot = lane >> 4;

  auto stage = [&](int b, int k0) {
    u16* a = &As[b * 4096];
    u16* bb = &Bs[b * 4096];
    glds16(pa0 + k0, a + t * 8);
    glds16(pa1 + k0, a + 2048 + t * 8);
    glds16(pb0 + k0, bb + t * 8);
    glds16(pb1 + k0, bb + 2048 + t * 8);
  };
  auto compute = [&](int b) {
    const u16* A = &As[b * 4096];
    const u16* Bb = &Bs[b * 4096];
    bf16x8 af[4], bfv[4];
#pragma unroll
    for (int mi = 0; mi < 4; mi++) {
      int row = wr + mi * 16 + lrow;
      af[mi] = *(const bf16x8*)&A[row * 32 + ((lslot ^ ((row >> 1) & 3)) * 8)];
    }
#pragma unroll
    for (int ni = 0; ni < 4; ni++) {
      int row = wc + ni * 16 + lrow;
      bfv[ni] = *(const bf16x8*)&Bb[row * 32 + ((lslot ^ ((row >> 1) & 3)) * 8)];
    }
#pragma unroll
    for (int mi = 0; mi < 4; mi++)
#pragma unroll
      for (int ni = 0; ni < 4; ni++)
        acc[mi][ni] = __builtin_amdgcn_mfma_f32_16x16x32_bf16(af[mi], bfv[ni], acc[mi][ni], 0, 0, 0);
  };

  const int nk = (IDIM / KS) / 32;  // 64
  stage(0, 0);
  for (int kt = 0; kt < nk; ++kt) {
    int b = kt & 1;
    __builtin_amdgcn_s_barrier();
    if (kt + 1 < nk) {
      stage(b ^ 1, (kt + 1) * 32);
      asm volatile("s_waitcnt vmcnt(4)" ::: "memory");
    } else {
      asm volatile("s_waitcnt vmcnt(0)" ::: "memory");
    }
    compute(b);
  }

  float bv[4];
#pragma unroll
  for (int ni = 0; ni < 4; ni++)
    bv[ni] = (ks == 0) ? bias[(size_t)e * HDIM + n0 + wc + ni * 16 + lrow] : 0.0f;
  int r4 = lslot * 4;
#pragma unroll
  for (int mi = 0; mi < 4; mi++) {
    int rb = m0 + wr + mi * 16 + r4;
#pragma unroll
    for (int j = 0; j < 4; j++) {
      int row = rb + j;
      if (row < cnt) {
        int tok = tlist[e * T_TOK + row];
        float w = wlist[e * T_TOK + row];
        float* op = out + (size_t)tok * HDIM + n0 + wc + lrow;
#pragma unroll
        for (int ni = 0; ni < 4; ni++)
          atomicAdd(&op[ni * 16], w * (acc[mi][ni][j] + bv[ni]));
      }
    }
  }
}

extern "C" void kernel_launch(void* const* d_in, const int* in_sizes, int n_in,
                              void* d_out, int out_size, void* d_ws, size_t ws_size,
                              hipStream_t stream) {
  const float* x   = (const float*)d_in[0];
  const float* gw  = (const float*)d_in[1];
  const float* upw = (const float*)d_in[2];
  const float* upb = (const float*)d_in[3];
  const float* dnw = (const float*)d_in[4];
  const float* dnb = (const float*)d_in[5];
  float* out = (float*)d_out;
  char* ws = (char*)d_ws;

  int*   counts = (int*)(ws + 0);
  int*   hbase  = (int*)(ws + 64);
  int*   tlist  = (int*)(ws + 256);
  float* wlist  = (float*)(ws + 256 + 262144);
  float* probs  = (float*)(ws + 256 + 2 * 262144);
  u16*   xb     = (u16*)(ws + 1048576);
  u16*   upbt   = (u16*)(ws + 1048576 + 16777216);
  u16*   dnbt   = (u16*)(ws + 1048576 + 16777216 + 67108864ull);
  u16*   hbuf   = (u16*)(ws + 1048576 + 16777216 + 2ull * 67108864ull);

  bool grouped = ws_size >= 286261248ull;

  hipMemsetAsync(counts, 0, 32, stream);
  hipMemsetAsync(d_out, 0, (size_t)out_size * 4, stream);

  transpose_cvt64<<<dim3(IDIM / 64, HDIM / 64, NEXP), 256, 0, stream>>>(upw, upbt, HDIM, IDIM);
  transpose_cvt64<<<dim3(HDIM / 64, IDIM / 64, NEXP), 256, 0, stream>>>(dnw, dnbt, IDIM, HDIM);
  router_kernel<<<T_TOK / 4, 256, 0, stream>>>(x, gw, xb, probs, counts, tlist, wlist, out);
  hbase_kernel<<<1, 64, 0, stream>>>(counts, hbase);
  usage_kernel<<<NEXP, 256, 0, stream>>>(probs, out);
  loss_kernel<<<1, 64, 0, stream>>>(out);

  if (grouped) {
    up_gemm<<<NEXP * 64 * 32, 256, 0, stream>>>(xb, upbt, upb, counts, hbase, tlist, hbuf, -1);
    down_gemm<<<NEXP * 64 * 8 * 2, 256, 0, stream>>>(hbuf, dnbt, dnb, counts, hbase, tlist, wlist, out, -1);
  } else {
    for (int e = 0; e < NEXP; e++) {
      up_gemm<<<64 * 32, 256, 0, stream>>>(xb, upbt, upb, counts, hbase, tlist, hbuf, e);
      down_gemm<<<64 * 8 * 2, 256, 0, stream>>>(hbuf, dnbt, dnb, counts, hbase, tlist, wlist, out, e);
    }
  }
}

// Round 13
// 759.193 us; speedup vs baseline: 1.1005x; 1.0109x over previous
//
#include <hip/hip_runtime.h>
#include <cmath>

#define T_TOK 8192
#define HDIM 1024
#define IDIM 4096
#define NEXP 8

#define OFF_LOSS  8388608
#define OFF_USAGE 8388609
#define OFF_TOPE  8388617

typedef __attribute__((ext_vector_type(8))) short bf16x8;
typedef __attribute__((ext_vector_type(4))) float f32x4;
typedef unsigned short u16;
typedef unsigned int u32;

__device__ inline u16 f2bf(float f) {
  u32 u = __float_as_uint(f);
  u32 r = (u + 0x7FFFu + ((u >> 16) & 1u)) >> 16;
  return (u16)r;
}

// tanh-form gelu via fast exp; max |err| vs exact-erf gelu ~3e-3 (budget 0.14).
__device__ inline float gelu_fast(float v) {
  float u = v + 0.044715f * v * v * v;
  return v / (1.0f + __expf(-1.5957691216f * u));
}

__device__ inline void glds16(const void* g, void* l) {
  __builtin_amdgcn_global_load_lds(
      (const __attribute__((address_space(1))) u32*)g,
      (__attribute__((address_space(3))) u32*)l, 16, 0, 0);
}

// ------- transpose+convert: src [E][R][C] f32 -> dst [E][C][R] bf16, 64x64 tile ------
__global__ __launch_bounds__(256)
void transpose_cvt64(const float* __restrict__ src, u16* __restrict__ dst, int R, int C) {
  __shared__ float tile[64][65];
  size_t eoff = (size_t)blockIdx.z * R * C;
  int r0 = blockIdx.y * 64, c0 = blockIdx.x * 64;
  const float* s = src + eoff;
  u16* d = dst + eoff;
  int tr = threadIdx.x >> 4;
  int tc = (threadIdx.x & 15) * 4;
#pragma unroll
  for (int it = 0; it < 4; it++) {
    int row = tr + it * 16;
    float4 v = *(const float4*)(s + (size_t)(r0 + row) * C + c0 + tc);
    tile[row][tc] = v.x; tile[row][tc + 1] = v.y;
    tile[row][tc + 2] = v.z; tile[row][tc + 3] = v.w;
  }
  __syncthreads();
  int wc = threadIdx.x >> 3;
  int wr = (threadIdx.x & 7) * 8;
#pragma unroll
  for (int it = 0; it < 2; it++) {
    int c = wc + it * 32;
    union { u16 s[8]; uint4 v; } u;
#pragma unroll
    for (int j = 0; j < 8; j++) u.s[j] = f2bf(tile[wr + j][c]);
    *(uint4*)(d + (size_t)(c0 + c) * R + r0 + wr) = u.v;
  }
}

// ---- router: f64 logits/softmax/top2, 4 tokens/block; also emits xb (bf16 x) ----
__global__ __launch_bounds__(256)
void router_kernel(const float* __restrict__ x, const float* __restrict__ gw,
                   u16* __restrict__ xb,
                   float* __restrict__ probs, int* __restrict__ counts,
                   int* __restrict__ tlist, float* __restrict__ wlist,
                   float* __restrict__ out) {
  int wid = threadIdx.x >> 6, lane = threadIdx.x & 63;
  int tok = blockIdx.x * 4 + wid;
  double acc[NEXP];
#pragma unroll
  for (int e = 0; e < NEXP; e++) acc[e] = 0.0;
  const float* xr = x + (size_t)tok * HDIM;
  u16* xbr = xb + (size_t)tok * HDIM;
#pragma unroll
  for (int i = 0; i < 4; i++) {
    int h0 = (lane + i * 64) * 4;
    float4 v = *(const float4*)(xr + h0);
    union { u16 s[4]; uint2 u; } cv;
    cv.s[0] = f2bf(v.x); cv.s[1] = f2bf(v.y);
    cv.s[2] = f2bf(v.z); cv.s[3] = f2bf(v.w);
    *(uint2*)(xbr + h0) = cv.u;
    const float* g0 = gw + (size_t)h0 * NEXP;
#pragma unroll
    for (int e = 0; e < NEXP; e++)
      acc[e] += (double)v.x * (double)g0[e] +
                (double)v.y * (double)g0[NEXP + e] +
                (double)v.z * (double)g0[2 * NEXP + e] +
                (double)v.w * (double)g0[3 * NEXP + e];
  }
#pragma unroll
  for (int off = 32; off > 0; off >>= 1) {
#pragma unroll
    for (int e = 0; e < NEXP; e++) acc[e] += __shfl_xor(acc[e], off);
  }
  if (lane == 0) {
    double m = acc[0];
#pragma unroll
    for (int e = 1; e < NEXP; e++) if (acc[e] > m) m = acc[e];
    double p[NEXP], ssum = 0.0;
#pragma unroll
    for (int e = 0; e < NEXP; e++) { p[e] = exp(acc[e] - m); ssum += p[e]; }
#pragma unroll
    for (int e = 0; e < NEXP; e++) p[e] /= ssum;
    int i1 = 0;
#pragma unroll
    for (int e = 1; e < NEXP; e++) if (p[e] > p[i1]) i1 = e;
    int i2 = (i1 == 0) ? 1 : 0;
#pragma unroll
    for (int e = 0; e < NEXP; e++) if (e != i1 && p[e] > p[i2]) i2 = e;
    double ps = p[i1] + p[i2];
#pragma unroll
    for (int e = 0; e < NEXP; e++) probs[(size_t)tok * NEXP + e] = (float)p[e];
    out[OFF_TOPE + tok] = (float)i1;
    int pos1 = atomicAdd(&counts[i1], 1);
    tlist[i1 * T_TOK + pos1] = tok;
    wlist[i1 * T_TOK + pos1] = (float)(p[i1] / ps);
    int pos2 = atomicAdd(&counts[i2], 1);
    tlist[i2 * T_TOK + pos2] = tok;
    wlist[i2 * T_TOK + pos2] = (float)(p[i2] / ps);
  }
}

__global__ __launch_bounds__(256)
void usage_kernel(const float* __restrict__ probs, float* __restrict__ out) {
  int e = blockIdx.x;
  float s = 0.f;
  for (int t = threadIdx.x; t < T_TOK; t += 256) s += probs[(size_t)t * NEXP + e];
#pragma unroll
  for (int off = 32; off > 0; off >>= 1) s += __shfl_xor(s, off);
  __shared__ float red[4];
  int lane = threadIdx.x & 63, wid = threadIdx.x >> 6;
  if (lane == 0) red[wid] = s;
  __syncthreads();
  if (threadIdx.x == 0)
    out[OFF_USAGE + e] = (red[0] + red[1] + red[2] + red[3]) / (float)T_TOK;
}

__global__ void loss_kernel(float* __restrict__ out) {
  if (threadIdx.x == 0 && blockIdx.x == 0) {
    float s = 0.f;
    for (int e = 0; e < NEXP; e++) { float u = out[OFF_USAGE + e]; s += u * u; }
    out[OFF_LOSS] = (float)NEXP * s;
  }
}

// ======== 128x128 BK=32 GEMMs, 256 thr (4 waves 2x2), dbuf 32KB, counted vmcnt ====
// Consolidated best-known config: up = R10 exact (bounds (256,3), e/tm/tn order);
// down = R12 (bounds (256,4), SPLIT-K=2, e/ks/tm/tn order, FETCH -26%).
// hbase computed inline per block (8-element prefix sum) -- hbase_kernel removed.

// ---------------- up GEMM: h = gelu(x[tok] @ up_w[e] + up_b[e]) ----------------
__global__ __launch_bounds__(256, 3)
void up_gemm(const u16* __restrict__ xb, const u16* __restrict__ wbt,
             const float* __restrict__ bias, const int* __restrict__ counts,
             const int* __restrict__ tlist,
             u16* __restrict__ hout, int e_fixed) {
  const int NT = IDIM / 128;   // 32
  const int MT = T_TOK / 128;  // 64
  int q = gridDim.x >> 3;
  int orig = blockIdx.x;
  int wg = (orig & 7) * q + (orig >> 3);   // XCD-chunked, bijective (nwg%8==0)
  int e, tm, tn;
  if (e_fixed >= 0) { e = e_fixed; tm = wg / NT; tn = wg % NT; }
  else { e = wg / (MT * NT); int r = wg % (MT * NT); tm = r / NT; tn = r % NT; }
  int cnt = counts[e];
  int m0 = tm * 128;
  if (m0 >= cnt) return;
  int hb = 0;
  if (e_fixed < 0) {
#pragma unroll
    for (int i = 0; i < NEXP; i++) if (i < e) hb += counts[i];
  }
  int n0 = tn * 128;

  __shared__ u16 As[2 * 4096];
  __shared__ u16 Bs[2 * 4096];

  int t = threadIdx.x;
  int ra = t >> 2;
  int sw = (t & 3) ^ ((ra >> 1) & 3);

  const int* tl = tlist + e * T_TOK;
  int g0 = m0 + ra;      if (g0 > cnt - 1) g0 = cnt - 1;
  int g1 = m0 + ra + 64; if (g1 > cnt - 1) g1 = cnt - 1;
  const u16* pa0 = xb + (size_t)tl[g0] * HDIM + sw * 8;
  const u16* pa1 = xb + (size_t)tl[g1] * HDIM + sw * 8;
  const u16* wb = wbt + (size_t)e * IDIM * HDIM;
  const u16* pb0 = wb + (size_t)(n0 + ra) * HDIM + sw * 8;
  const u16* pb1 = wb + (size_t)(n0 + ra + 64) * HDIM + sw * 8;

  f32x4 acc[4][4];
#pragma unroll
  for (int i = 0; i < 4; i++)
#pragma unroll
    for (int j = 0; j < 4; j++) acc[i][j] = (f32x4){0.f, 0.f, 0.f, 0.f};

  int lane = t & 63, wid = t >> 6;
  int wr = (wid >> 1) * 64, wc = (wid & 1) * 64;
  int lrow = lane & 15, lslot = lane >> 4;

  auto stage = [&](int b, int k0) {
    u16* a = &As[b * 4096];
    u16* bb = &Bs[b * 4096];
    glds16(pa0 + k0, a + t * 8);
    glds16(pa1 + k0, a + 2048 + t * 8);
    glds16(pb0 + k0, bb + t * 8);
    glds16(pb1 + k0, bb + 2048 + t * 8);
  };
  auto compute = [&](int b) {
    const u16* A = &As[b * 4096];
    const u16* Bb = &Bs[b * 4096];
    bf16x8 af[4], bfv[4];
#pragma unroll
    for (int mi = 0; mi < 4; mi++) {
      int row = wr + mi * 16 + lrow;
      af[mi] = *(const bf16x8*)&A[row * 32 + ((lslot ^ ((row >> 1) & 3)) * 8)];
    }
#pragma unroll
    for (int ni = 0; ni < 4; ni++) {
      int row = wc + ni * 16 + lrow;
      bfv[ni] = *(const bf16x8*)&Bb[row * 32 + ((lslot ^ ((row >> 1) & 3)) * 8)];
    }
#pragma unroll
    for (int mi = 0; mi < 4; mi++)
#pragma unroll
      for (int ni = 0; ni < 4; ni++)
        acc[mi][ni] = __builtin_amdgcn_mfma_f32_16x16x32_bf16(af[mi], bfv[ni], acc[mi][ni], 0, 0, 0);
  };

  const int nk = HDIM / 32;  // 32
  stage(0, 0);
  for (int kt = 0; kt < nk; ++kt) {
    int b = kt & 1;
    __builtin_amdgcn_s_barrier();
    if (kt + 1 < nk) {
      stage(b ^ 1, (kt + 1) * 32);
      asm volatile("s_waitcnt vmcnt(4)" ::: "memory");
    } else {
      asm volatile("s_waitcnt vmcnt(0)" ::: "memory");
    }
    compute(b);
  }

  float bv[4];
#pragma unroll
  for (int ni = 0; ni < 4; ni++)
    bv[ni] = bias[(size_t)e * IDIM + n0 + wc + ni * 16 + lrow];
  int r4 = lslot * 4;
#pragma unroll
  for (int mi = 0; mi < 4; mi++) {
    int rb = m0 + wr + mi * 16 + r4;
#pragma unroll
    for (int j = 0; j < 4; j++) {
      int row = rb + j;
      if (row < cnt) {
        u16* hp = hout + (size_t)(hb + row) * IDIM + n0 + wc + lrow;
#pragma unroll
        for (int ni = 0; ni < 4; ni++) {
          float v = acc[mi][ni][j] + bv[ni];
          hp[ni * 16] = f2bf(gelu_fast(v));
        }
      }
    }
  }
}

// ------- down GEMM, SPLIT-K=2: out[tok] += w * (h @ down_w[e] + down_b[e]) -------
// Tile order: e / ks / tm / tn (tn inner).
__global__ __launch_bounds__(256, 4)
void down_gemm(const u16* __restrict__ h, const u16* __restrict__ wbt,
               const float* __restrict__ bias, const int* __restrict__ counts,
               const int* __restrict__ tlist,
               const float* __restrict__ wlist, float* __restrict__ out, int e_fixed) {
  const int NT = HDIM / 128;   // 8
  const int MT = T_TOK / 128;  // 64
  const int KS = 2;
  int q = gridDim.x >> 3;
  int orig = blockIdx.x;
  int wg = (orig & 7) * q + (orig >> 3);
  int e, r;
  if (e_fixed >= 0) { e = e_fixed; r = wg; }
  else { e = wg / (KS * MT * NT); r = wg % (KS * MT * NT); }
  int ks = r / (MT * NT);
  int r2 = r % (MT * NT);
  int tm = r2 / NT;
  int tn = r2 % NT;
  int cnt = counts[e];
  int m0 = tm * 128;
  if (m0 >= cnt) return;
  int hb = 0;
  if (e_fixed < 0) {
#pragma unroll
    for (int i = 0; i < NEXP; i++) if (i < e) hb += counts[i];
  }
  int n0 = tn * 128;
  int kbase = ks * (IDIM / KS);   // 0 or 2048

  __shared__ u16 As[2 * 4096];
  __shared__ u16 Bs[2 * 4096];

  int t = threadIdx.x;
  int ra = t >> 2;
  int sw = (t & 3) ^ ((ra >> 1) & 3);

  int g0 = m0 + ra;      if (g0 > cnt - 1) g0 = cnt - 1;
  int g1 = m0 + ra + 64; if (g1 > cnt - 1) g1 = cnt - 1;
  const u16* pa0 = h + (size_t)(hb + g0) * IDIM + kbase + sw * 8;
  const u16* pa1 = h + (size_t)(hb + g1) * IDIM + kbase + sw * 8;
  const u16* wb = wbt + (size_t)e * HDIM * IDIM;
  const u16* pb0 = wb + (size_t)(n0 + ra) * IDIM + kbase + sw * 8;
  const u16* pb1 = wb + (size_t)(n0 + ra + 64) * IDIM + kbase + sw * 8;

  f32x4 acc[4][4];
#pragma unroll
  for (int i = 0; i < 4; i++)
#pragma unroll
    for (int j = 0; j < 4; j++) acc[i][j] = (f32x4){0.f, 0.f, 0.f, 0.f};

  int lane = t & 63, wid = t >> 6;
  int wr = (wid >> 1) * 64, wc = (wid & 1) * 64;
  int lrow = lane & 15, lslot = lane >> 4;

  auto stage = [&](int b, int k0) {
    u16* a = &As[b * 4096];
    u16* bb = &Bs[b * 4096];
    glds16(pa0 + k0, a + t * 8);
    glds16(pa1 + k0, a + 2048 + t * 8);
    glds16(pb0 + k0, bb + t * 8);
    glds16(pb1 + k0, bb + 2048 + t * 8);
  };
  auto compute = [&](int b) {
    const u16* A = &As[b * 4096];
    const u16* Bb = &Bs[b * 4096];
    bf16x8 af[4], bfv[4];
#pragma unroll
    for (int mi = 0; mi < 4; mi++) {
      int row = wr + mi * 16 + lrow;
      af[mi] = *(const bf16x8*)&A[row * 32 + ((lslot ^ ((row >> 1) & 3)) * 8)];
    }
#pragma unroll
    for (int ni = 0; ni < 4; ni++) {
      int row = wc + ni * 16 + lrow;
      bfv[ni] = *(const bf16x8*)&Bb[row * 32 + ((lslot ^ ((row >> 1) & 3)) * 8)];
    }
#pragma unroll
    for (int mi = 0; mi < 4; mi++)
#pragma unroll
      for (int ni = 0; ni < 4; ni++)
        acc[mi][ni] = __builtin_amdgcn_mfma_f32_16x16x32_bf16(af[mi], bfv[ni], acc[mi][ni], 0, 0, 0);
  };

  const int nk = (IDIM / KS) / 32;  // 64
  stage(0, 0);
  for (int kt = 0; kt < nk; ++kt) {
    int b = kt & 1;
    __builtin_amdgcn_s_barrier();
    if (kt + 1 < nk) {
      stage(b ^ 1, (kt + 1) * 32);
      asm volatile("s_waitcnt vmcnt(4)" ::: "memory");
    } else {
      asm volatile("s_waitcnt vmcnt(0)" ::: "memory");
    }
    compute(b);
  }

  float bv[4];
#pragma unroll
  for (int ni = 0; ni < 4; ni++)
    bv[ni] = (ks == 0) ? bias[(size_t)e * HDIM + n0 + wc + ni * 16 + lrow] : 0.0f;
  int r4 = lslot * 4;
#pragma unroll
  for (int mi = 0; mi < 4; mi++) {
    int rb = m0 + wr + mi * 16 + r4;
#pragma unroll
    for (int j = 0; j < 4; j++) {
      int row = rb + j;
      if (row < cnt) {
        int tok = tlist[e * T_TOK + row];
        float w = wlist[e * T_TOK + row];
        float* op = out + (size_t)tok * HDIM + n0 + wc + lrow;
#pragma unroll
        for (int ni = 0; ni < 4; ni++)
          atomicAdd(&op[ni * 16], w * (acc[mi][ni][j] + bv[ni]));
      }
    }
  }
}

extern "C" void kernel_launch(void* const* d_in, const int* in_sizes, int n_in,
                              void* d_out, int out_size, void* d_ws, size_t ws_size,
                              hipStream_t stream) {
  const float* x   = (const float*)d_in[0];
  const float* gw  = (const float*)d_in[1];
  const float* upw = (const float*)d_in[2];
  const float* upb = (const float*)d_in[3];
  const float* dnw = (const float*)d_in[4];
  const float* dnb = (const float*)d_in[5];
  float* out = (float*)d_out;
  char* ws = (char*)d_ws;

  int*   counts = (int*)(ws + 0);
  int*   tlist  = (int*)(ws + 256);
  float* wlist  = (float*)(ws + 256 + 262144);
  float* probs  = (float*)(ws + 256 + 2 * 262144);
  u16*   xb     = (u16*)(ws + 1048576);
  u16*   upbt   = (u16*)(ws + 1048576 + 16777216);
  u16*   dnbt   = (u16*)(ws + 1048576 + 16777216 + 67108864ull);
  u16*   hbuf   = (u16*)(ws + 1048576 + 16777216 + 2ull * 67108864ull);

  bool grouped = ws_size >= 286261248ull;

  hipMemsetAsync(counts, 0, 32, stream);
  hipMemsetAsync(d_out, 0, (size_t)out_size * 4, stream);

  transpose_cvt64<<<dim3(IDIM / 64, HDIM / 64, NEXP), 256, 0, stream>>>(upw, upbt, HDIM, IDIM);
  transpose_cvt64<<<dim3(HDIM / 64, IDIM / 64, NEXP), 256, 0, stream>>>(dnw, dnbt, IDIM, HDIM);
  router_kernel<<<T_TOK / 4, 256, 0, stream>>>(x, gw, xb, probs, counts, tlist, wlist, out);
  usage_kernel<<<NEXP, 256, 0, stream>>>(probs, out);
  loss_kernel<<<1, 64, 0, stream>>>(out);

  if (grouped) {
    up_gemm<<<NEXP * 64 * 32, 256, 0, stream>>>(xb, upbt, upb, counts, tlist, hbuf, -1);
    down_gemm<<<NEXP * 64 * 8 * 2, 256, 0, stream>>>(hbuf, dnbt, dnb, counts, tlist, wlist, out, -1);
  } else {
    for (int e = 0; e < NEXP; e++) {
      up_gemm<<<64 * 32, 256, 0, stream>>>(xb, upbt, upb, counts, tlist, hbuf, e);
      down_gemm<<<64 * 8 * 2, 256, 0, stream>>>(hbuf, dnbt, dnb, counts, tlist, wlist, out, e);
    }
  }
}

// Round 14
// 757.874 us; speedup vs baseline: 1.1024x; 1.0017x over previous
//
#include <hip/hip_runtime.h>
#include <cmath>

#define T_TOK 8192
#define HDIM 1024
#define IDIM 4096
#define NEXP 8

#define OFF_LOSS  8388608
#define OFF_USAGE 8388609
#define OFF_TOPE  8388617

typedef __attribute__((ext_vector_type(8))) short bf16x8;
typedef __attribute__((ext_vector_type(4))) float f32x4;
typedef unsigned short u16;
typedef unsigned int u32;

__device__ inline u16 f2bf(float f) {
  u32 u = __float_as_uint(f);
  u32 r = (u + 0x7FFFu + ((u >> 16) & 1u)) >> 16;
  return (u16)r;
}

// tanh-form gelu via fast exp; max |err| vs exact-erf gelu ~3e-3 (budget 0.14).
__device__ inline float gelu_fast(float v) {
  float u = v + 0.044715f * v * v * v;
  return v / (1.0f + __expf(-1.5957691216f * u));
}

__device__ inline void glds16(const void* g, void* l) {
  __builtin_amdgcn_global_load_lds(
      (const __attribute__((address_space(1))) u32*)g,
      (__attribute__((address_space(3))) u32*)l, 16, 0, 0);
}

// ---- transpose+convert v3: src [E][R][C] f32 -> dst [E][C][R] bf16 ----
// 128(src rows) x 64(src cols) per block. Convert f32->bf16 INTO LDS with a
// transposed store ([col][row], 272B row stride: reads 16B-aligned, writes
// <=4-way banks, reads 2-way). dst writes: 256B contiguous per dst row
// (16 lanes x 16B), 4 rows/wave/instr. Global volume dominates -> ~BW-bound.
__global__ __launch_bounds__(256)
void transpose_cvt128(const float* __restrict__ src, u16* __restrict__ dst,
                      int R, int C) {
  __shared__ u16 lt[64][136];   // [src-col][src-row], stride 272B = 17x16B
  size_t eoff = (size_t)blockIdx.z * R * C;
  int r0 = blockIdx.y * 128, c0 = blockIdx.x * 64;
  const float* s = src + eoff;
  u16* d = dst + eoff;
  int tr = threadIdx.x >> 4;          // 0..15
  int tc = (threadIdx.x & 15) * 4;    // 0..60
#pragma unroll
  for (int it = 0; it < 8; it++) {
    int row = tr + it * 16;           // 0..127
    float4 v = *(const float4*)(s + (size_t)(r0 + row) * C + c0 + tc);
    lt[tc    ][row] = f2bf(v.x);
    lt[tc + 1][row] = f2bf(v.y);
    lt[tc + 2][row] = f2bf(v.z);
    lt[tc + 3][row] = f2bf(v.w);
  }
  __syncthreads();
  int cc = threadIdx.x >> 4;          // 0..15
  int rr = (threadIdx.x & 15) * 8;    // 0..120
#pragma unroll
  for (int p = 0; p < 4; p++) {
    int c = p * 16 + cc;
    *(uint4*)(d + (size_t)(c0 + c) * R + r0 + rr) = *(const uint4*)&lt[c][rr];
  }
}

// ---- router: f64 logits/softmax/top2, 4 tokens/block; also emits xb (bf16 x) ----
__global__ __launch_bounds__(256)
void router_kernel(const float* __restrict__ x, const float* __restrict__ gw,
                   u16* __restrict__ xb,
                   float* __restrict__ probs, int* __restrict__ counts,
                   int* __restrict__ tlist, float* __restrict__ wlist,
                   float* __restrict__ out) {
  int wid = threadIdx.x >> 6, lane = threadIdx.x & 63;
  int tok = blockIdx.x * 4 + wid;
  double acc[NEXP];
#pragma unroll
  for (int e = 0; e < NEXP; e++) acc[e] = 0.0;
  const float* xr = x + (size_t)tok * HDIM;
  u16* xbr = xb + (size_t)tok * HDIM;
#pragma unroll
  for (int i = 0; i < 4; i++) {
    int h0 = (lane + i * 64) * 4;
    float4 v = *(const float4*)(xr + h0);
    union { u16 s[4]; uint2 u; } cv;
    cv.s[0] = f2bf(v.x); cv.s[1] = f2bf(v.y);
    cv.s[2] = f2bf(v.z); cv.s[3] = f2bf(v.w);
    *(uint2*)(xbr + h0) = cv.u;
    const float* g0 = gw + (size_t)h0 * NEXP;
#pragma unroll
    for (int e = 0; e < NEXP; e++)
      acc[e] += (double)v.x * (double)g0[e] +
                (double)v.y * (double)g0[NEXP + e] +
                (double)v.z * (double)g0[2 * NEXP + e] +
                (double)v.w * (double)g0[3 * NEXP + e];
  }
#pragma unroll
  for (int off = 32; off > 0; off >>= 1) {
#pragma unroll
    for (int e = 0; e < NEXP; e++) acc[e] += __shfl_xor(acc[e], off);
  }
  if (lane == 0) {
    double m = acc[0];
#pragma unroll
    for (int e = 1; e < NEXP; e++) if (acc[e] > m) m = acc[e];
    double p[NEXP], ssum = 0.0;
#pragma unroll
    for (int e = 0; e < NEXP; e++) { p[e] = exp(acc[e] - m); ssum += p[e]; }
#pragma unroll
    for (int e = 0; e < NEXP; e++) p[e] /= ssum;
    int i1 = 0;
#pragma unroll
    for (int e = 1; e < NEXP; e++) if (p[e] > p[i1]) i1 = e;
    int i2 = (i1 == 0) ? 1 : 0;
#pragma unroll
    for (int e = 0; e < NEXP; e++) if (e != i1 && p[e] > p[i2]) i2 = e;
    double ps = p[i1] + p[i2];
#pragma unroll
    for (int e = 0; e < NEXP; e++) probs[(size_t)tok * NEXP + e] = (float)p[e];
    out[OFF_TOPE + tok] = (float)i1;
    int pos1 = atomicAdd(&counts[i1], 1);
    tlist[i1 * T_TOK + pos1] = tok;
    wlist[i1 * T_TOK + pos1] = (float)(p[i1] / ps);
    int pos2 = atomicAdd(&counts[i2], 1);
    tlist[i2 * T_TOK + pos2] = tok;
    wlist[i2 * T_TOK + pos2] = (float)(p[i2] / ps);
  }
}

// ---- usage + loss fused: one block, vectorized probs reads ----
__global__ __launch_bounds__(256)
void usage_loss_kernel(const float* __restrict__ probs, float* __restrict__ out) {
  float se[NEXP];
#pragma unroll
  for (int e = 0; e < NEXP; e++) se[e] = 0.f;
  for (int tok = threadIdx.x; tok < T_TOK; tok += 256) {
    const float* p = probs + (size_t)tok * NEXP;
    float4 a = *(const float4*)p;
    float4 b = *(const float4*)(p + 4);
    se[0] += a.x; se[1] += a.y; se[2] += a.z; se[3] += a.w;
    se[4] += b.x; se[5] += b.y; se[6] += b.z; se[7] += b.w;
  }
#pragma unroll
  for (int off = 32; off > 0; off >>= 1) {
#pragma unroll
    for (int e = 0; e < NEXP; e++) se[e] += __shfl_xor(se[e], off);
  }
  __shared__ float red[4][NEXP];
  int lane = threadIdx.x & 63, wid = threadIdx.x >> 6;
  if (lane == 0) {
#pragma unroll
    for (int e = 0; e < NEXP; e++) red[wid][e] = se[e];
  }
  __syncthreads();
  if (threadIdx.x == 0) {
    float loss = 0.f;
#pragma unroll
    for (int e = 0; e < NEXP; e++) {
      float u = (red[0][e] + red[1][e] + red[2][e] + red[3][e]) / (float)T_TOK;
      out[OFF_USAGE + e] = u;
      loss += u * u;
    }
    out[OFF_LOSS] = (float)NEXP * loss;
  }
}

// ======== 128x128 BK=32 GEMMs, 256 thr (4 waves 2x2), dbuf 32KB, counted vmcnt ====
// FROZEN at R13 (session-best, reproduced 3x): up = (256,3), e/tm/tn;
// down = (256,4), SPLIT-K=2, e/ks/tm/tn; inline hbase prefix sum.

// ---------------- up GEMM: h = gelu(x[tok] @ up_w[e] + up_b[e]) ----------------
__global__ __launch_bounds__(256, 3)
void up_gemm(const u16* __restrict__ xb, const u16* __restrict__ wbt,
             const float* __restrict__ bias, const int* __restrict__ counts,
             const int* __restrict__ tlist,
             u16* __restrict__ hout, int e_fixed) {
  const int NT = IDIM / 128;   // 32
  const int MT = T_TOK / 128;  // 64
  int q = gridDim.x >> 3;
  int orig = blockIdx.x;
  int wg = (orig & 7) * q + (orig >> 3);   // XCD-chunked, bijective (nwg%8==0)
  int e, tm, tn;
  if (e_fixed >= 0) { e = e_fixed; tm = wg / NT; tn = wg % NT; }
  else { e = wg / (MT * NT); int r = wg % (MT * NT); tm = r / NT; tn = r % NT; }
  int cnt = counts[e];
  int m0 = tm * 128;
  if (m0 >= cnt) return;
  int hb = 0;
  if (e_fixed < 0) {
#pragma unroll
    for (int i = 0; i < NEXP; i++) if (i < e) hb += counts[i];
  }
  int n0 = tn * 128;

  __shared__ u16 As[2 * 4096];
  __shared__ u16 Bs[2 * 4096];

  int t = threadIdx.x;
  int ra = t >> 2;
  int sw = (t & 3) ^ ((ra >> 1) & 3);

  const int* tl = tlist + e * T_TOK;
  int g0 = m0 + ra;      if (g0 > cnt - 1) g0 = cnt - 1;
  int g1 = m0 + ra + 64; if (g1 > cnt - 1) g1 = cnt - 1;
  const u16* pa0 = xb + (size_t)tl[g0] * HDIM + sw * 8;
  const u16* pa1 = xb + (size_t)tl[g1] * HDIM + sw * 8;
  const u16* wb = wbt + (size_t)e * IDIM * HDIM;
  const u16* pb0 = wb + (size_t)(n0 + ra) * HDIM + sw * 8;
  const u16* pb1 = wb + (size_t)(n0 + ra + 64) * HDIM + sw * 8;

  f32x4 acc[4][4];
#pragma unroll
  for (int i = 0; i < 4; i++)
#pragma unroll
    for (int j = 0; j < 4; j++) acc[i][j] = (f32x4){0.f, 0.f, 0.f, 0.f};

  int lane = t & 63, wid = t >> 6;
  int wr = (wid >> 1) * 64, wc = (wid & 1) * 64;
  int lrow = lane & 15, lslot = lane >> 4;

  auto stage = [&](int b, int k0) {
    u16* a = &As[b * 4096];
    u16* bb = &Bs[b * 4096];
    glds16(pa0 + k0, a + t * 8);
    glds16(pa1 + k0, a + 2048 + t * 8);
    glds16(pb0 + k0, bb + t * 8);
    glds16(pb1 + k0, bb + 2048 + t * 8);
  };
  auto compute = [&](int b) {
    const u16* A = &As[b * 4096];
    const u16* Bb = &Bs[b * 4096];
    bf16x8 af[4], bfv[4];
#pragma unroll
    for (int mi = 0; mi < 4; mi++) {
      int row = wr + mi * 16 + lrow;
      af[mi] = *(const bf16x8*)&A[row * 32 + ((lslot ^ ((row >> 1) & 3)) * 8)];
    }
#pragma unroll
    for (int ni = 0; ni < 4; ni++) {
      int row = wc + ni * 16 + lrow;
      bfv[ni] = *(const bf16x8*)&Bb[row * 32 + ((lslot ^ ((row >> 1) & 3)) * 8)];
    }
#pragma unroll
    for (int mi = 0; mi < 4; mi++)
#pragma unroll
      for (int ni = 0; ni < 4; ni++)
        acc[mi][ni] = __builtin_amdgcn_mfma_f32_16x16x32_bf16(af[mi], bfv[ni], acc[mi][ni], 0, 0, 0);
  };

  const int nk = HDIM / 32;  // 32
  stage(0, 0);
  for (int kt = 0; kt < nk; ++kt) {
    int b = kt & 1;
    __builtin_amdgcn_s_barrier();
    if (kt + 1 < nk) {
      stage(b ^ 1, (kt + 1) * 32);
      asm volatile("s_waitcnt vmcnt(4)" ::: "memory");
    } else {
      asm volatile("s_waitcnt vmcnt(0)" ::: "memory");
    }
    compute(b);
  }

  float bv[4];
#pragma unroll
  for (int ni = 0; ni < 4; ni++)
    bv[ni] = bias[(size_t)e * IDIM + n0 + wc + ni * 16 + lrow];
  int r4 = lslot * 4;
#pragma unroll
  for (int mi = 0; mi < 4; mi++) {
    int rb = m0 + wr + mi * 16 + r4;
#pragma unroll
    for (int j = 0; j < 4; j++) {
      int row = rb + j;
      if (row < cnt) {
        u16* hp = hout + (size_t)(hb + row) * IDIM + n0 + wc + lrow;
#pragma unroll
        for (int ni = 0; ni < 4; ni++) {
          float v = acc[mi][ni][j] + bv[ni];
          hp[ni * 16] = f2bf(gelu_fast(v));
        }
      }
    }
  }
}

// ------- down GEMM, SPLIT-K=2: out[tok] += w * (h @ down_w[e] + down_b[e]) -------
__global__ __launch_bounds__(256, 4)
void down_gemm(const u16* __restrict__ h, const u16* __restrict__ wbt,
               const float* __restrict__ bias, const int* __restrict__ counts,
               const int* __restrict__ tlist,
               const float* __restrict__ wlist, float* __restrict__ out, int e_fixed) {
  const int NT = HDIM / 128;   // 8
  const int MT = T_TOK / 128;  // 64
  const int KS = 2;
  int q = gridDim.x >> 3;
  int orig = blockIdx.x;
  int wg = (orig & 7) * q + (orig >> 3);
  int e, r;
  if (e_fixed >= 0) { e = e_fixed; r = wg; }
  else { e = wg / (KS * MT * NT); r = wg % (KS * MT * NT); }
  int ks = r / (MT * NT);
  int r2 = r % (MT * NT);
  int tm = r2 / NT;
  int tn = r2 % NT;
  int cnt = counts[e];
  int m0 = tm * 128;
  if (m0 >= cnt) return;
  int hb = 0;
  if (e_fixed < 0) {
#pragma unroll
    for (int i = 0; i < NEXP; i++) if (i < e) hb += counts[i];
  }
  int n0 = tn * 128;
  int kbase = ks * (IDIM / KS);   // 0 or 2048

  __shared__ u16 As[2 * 4096];
  __shared__ u16 Bs[2 * 4096];

  int t = threadIdx.x;
  int ra = t >> 2;
  int sw = (t & 3) ^ ((ra >> 1) & 3);

  int g0 = m0 + ra;      if (g0 > cnt - 1) g0 = cnt - 1;
  int g1 = m0 + ra + 64; if (g1 > cnt - 1) g1 = cnt - 1;
  const u16* pa0 = h + (size_t)(hb + g0) * IDIM + kbase + sw * 8;
  const u16* pa1 = h + (size_t)(hb + g1) * IDIM + kbase + sw * 8;
  const u16* wb = wbt + (size_t)e * HDIM * IDIM;
  const u16* pb0 = wb + (size_t)(n0 + ra) * IDIM + kbase + sw * 8;
  const u16* pb1 = wb + (size_t)(n0 + ra + 64) * IDIM + kbase + sw * 8;

  f32x4 acc[4][4];
#pragma unroll
  for (int i = 0; i < 4; i++)
#pragma unroll
    for (int j = 0; j < 4; j++) acc[i][j] = (f32x4){0.f, 0.f, 0.f, 0.f};

  int lane = t & 63, wid = t >> 6;
  int wr = (wid >> 1) * 64, wc = (wid & 1) * 64;
  int lrow = lane & 15, lslot = lane >> 4;

  auto stage = [&](int b, int k0) {
    u16* a = &As[b * 4096];
    u16* bb = &Bs[b * 4096];
    glds16(pa0 + k0, a + t * 8);
    glds16(pa1 + k0, a + 2048 + t * 8);
    glds16(pb0 + k0, bb + t * 8);
    glds16(pb1 + k0, bb + 2048 + t * 8);
  };
  auto compute = [&](int b) {
    const u16* A = &As[b * 4096];
    const u16* Bb = &Bs[b * 4096];
    bf16x8 af[4], bfv[4];
#pragma unroll
    for (int mi = 0; mi < 4; mi++) {
      int row = wr + mi * 16 + lrow;
      af[mi] = *(const bf16x8*)&A[row * 32 + ((lslot ^ ((row >> 1) & 3)) * 8)];
    }
#pragma unroll
    for (int ni = 0; ni < 4; ni++) {
      int row = wc + ni * 16 + lrow;
      bfv[ni] = *(const bf16x8*)&Bb[row * 32 + ((lslot ^ ((row >> 1) & 3)) * 8)];
    }
#pragma unroll
    for (int mi = 0; mi < 4; mi++)
#pragma unroll
      for (int ni = 0; ni < 4; ni++)
        acc[mi][ni] = __builtin_amdgcn_mfma_f32_16x16x32_bf16(af[mi], bfv[ni], acc[mi][ni], 0, 0, 0);
  };

  const int nk = (IDIM / KS) / 32;  // 64
  stage(0, 0);
  for (int kt = 0; kt < nk; ++kt) {
    int b = kt & 1;
    __builtin_amdgcn_s_barrier();
    if (kt + 1 < nk) {
      stage(b ^ 1, (kt + 1) * 32);
      asm volatile("s_waitcnt vmcnt(4)" ::: "memory");
    } else {
      asm volatile("s_waitcnt vmcnt(0)" ::: "memory");
    }
    compute(b);
  }

  float bv[4];
#pragma unroll
  for (int ni = 0; ni < 4; ni++)
    bv[ni] = (ks == 0) ? bias[(size_t)e * HDIM + n0 + wc + ni * 16 + lrow] : 0.0f;
  int r4 = lslot * 4;
#pragma unroll
  for (int mi = 0; mi < 4; mi++) {
    int rb = m0 + wr + mi * 16 + r4;
#pragma unroll
    for (int j = 0; j < 4; j++) {
      int row = rb + j;
      if (row < cnt) {
        int tok = tlist[e * T_TOK + row];
        float w = wlist[e * T_TOK + row];
        float* op = out + (size_t)tok * HDIM + n0 + wc + lrow;
#pragma unroll
        for (int ni = 0; ni < 4; ni++)
          atomicAdd(&op[ni * 16], w * (acc[mi][ni][j] + bv[ni]));
      }
    }
  }
}

extern "C" void kernel_launch(void* const* d_in, const int* in_sizes, int n_in,
                              void* d_out, int out_size, void* d_ws, size_t ws_size,
                              hipStream_t stream) {
  const float* x   = (const float*)d_in[0];
  const float* gw  = (const float*)d_in[1];
  const float* upw = (const float*)d_in[2];
  const float* upb = (const float*)d_in[3];
  const float* dnw = (const float*)d_in[4];
  const float* dnb = (const float*)d_in[5];
  float* out = (float*)d_out;
  char* ws = (char*)d_ws;

  int*   counts = (int*)(ws + 0);
  int*   tlist  = (int*)(ws + 256);
  float* wlist  = (float*)(ws + 256 + 262144);
  float* probs  = (float*)(ws + 256 + 2 * 262144);
  u16*   xb     = (u16*)(ws + 1048576);
  u16*   upbt   = (u16*)(ws + 1048576 + 16777216);
  u16*   dnbt   = (u16*)(ws + 1048576 + 16777216 + 67108864ull);
  u16*   hbuf   = (u16*)(ws + 1048576 + 16777216 + 2ull * 67108864ull);

  bool grouped = ws_size >= 286261248ull;

  hipMemsetAsync(counts, 0, 32, stream);
  hipMemsetAsync(d_out, 0, (size_t)out_size * 4, stream);

  transpose_cvt128<<<dim3(IDIM / 64, HDIM / 128, NEXP), 256, 0, stream>>>(upw, upbt, HDIM, IDIM);
  transpose_cvt128<<<dim3(HDIM / 64, IDIM / 128, NEXP), 256, 0, stream>>>(dnw, dnbt, IDIM, HDIM);
  router_kernel<<<T_TOK / 4, 256, 0, stream>>>(x, gw, xb, probs, counts, tlist, wlist, out);
  usage_loss_kernel<<<1, 256, 0, stream>>>(probs, out);

  if (grouped) {
    up_gemm<<<NEXP * 64 * 32, 256, 0, stream>>>(xb, upbt, upb, counts, tlist, hbuf, -1);
    down_gemm<<<NEXP * 64 * 8 * 2, 256, 0, stream>>>(hbuf, dnbt, dnb, counts, tlist, wlist, out, -1);
  } else {
    for (int e = 0; e < NEXP; e++) {
      up_gemm<<<64 * 32, 256, 0, stream>>>(xb, upbt, upb, counts, tlist, hbuf, e);
      down_gemm<<<64 * 8 * 2, 256, 0, stream>>>(hbuf, dnbt, dnb, counts, tlist, wlist, out, e);
    }
  }
}